// Round 6
// baseline (399.688 us; speedup 1.0000x reference)
//
#include <hip/hip_runtime.h>
#include <math.h>

// ---------------- problem constants ----------------
namespace {
constexpr int B_   = 2;
constexpr int NCAM = 6;
constexpr int BN   = 12;
constexpr int CIN  = 256;
constexpr int COUT = 80;
constexpr int DBIN = 16;
constexpr int NOUT = 96;            // DBIN + COUT
constexpr int HF = 32, WF = 88;
constexpr int HW = HF * WF;         // 2816
constexpr int BEVH = 128, BEVW = 128;
constexpr int NUMC = B_ * BEVH * BEVW;   // 32768
constexpr int NPTS = BN * DBIN * HW;     // 540672

// ws layout (byte offsets)
constexpr size_t MATS_OFF   = 0;                            // 12*24 f32
constexpr size_t WT_OFF     = 2048;                         // 24576 f32 = 98304
constexpr size_t YT_OFF     = 102400;                       // 12*2816*96 f32 = 12976128
                                                            // (reused as bevCHW after gather)
constexpr size_t CELL_OFF   = YT_OFF + 12976128;            // NPTS i32 = 2162688
constexpr size_t COUNTS_OFF = CELL_OFF + 2162688;           // NUMC i32 = 131072
constexpr size_t STARTS_OFF = COUNTS_OFF + 131072;          // (NUMC+1) i32, padded
constexpr size_t CURS_OFF   = STARTS_OFF + 131584;          // NUMC i32
constexpr size_t PLIST_OFF  = CURS_OFF + 131072;            // NPTS i32 (fused (row<<4)|d)
constexpr size_t PCELL_OFF  = PLIST_OFF + 2162688;          // NPTS i32 (cell per sorted pos)
constexpr size_t BEVHWC_OFF = PCELL_OFF + 2162688;          // NUMC*80 f32 = 10485760
}

// ---------------- f32 LU inverse, LAPACK gesv-style ----------------
template<int NM>
__device__ void inv_lu_f32(float* A, float* Y) {
    int piv[NM];
    for (int j = 0; j < NM; j++) {
        int p = j; float mx = fabsf(A[j*NM+j]);
        for (int i = j+1; i < NM; i++) { float v = fabsf(A[i*NM+j]); if (v > mx) { mx = v; p = i; } }
        piv[j] = p;
        if (p != j) for (int k = 0; k < NM; k++) { float t = A[j*NM+k]; A[j*NM+k] = A[p*NM+k]; A[p*NM+k] = t; }
        float r = __fdiv_rn(1.0f, A[j*NM+j]);
        for (int i = j+1; i < NM; i++) A[i*NM+j] = __fmul_rn(A[i*NM+j], r);
        for (int i = j+1; i < NM; i++) {
            float lij = A[i*NM+j];
            for (int k = j+1; k < NM; k++)
                A[i*NM+k] = __fsub_rn(A[i*NM+k], __fmul_rn(lij, A[j*NM+k]));
        }
    }
    for (int c = 0; c < NM; c++) {
        float x[NM];
        for (int i = 0; i < NM; i++) x[i] = 0.f;
        x[c] = 1.f;
        for (int j = 0; j < NM; j++) { int p = piv[j]; if (p != j) { float t = x[j]; x[j] = x[p]; x[p] = t; } }
        for (int k = 0; k < NM; k++) {
            float xk = x[k];
            for (int i = k+1; i < NM; i++) x[i] = __fsub_rn(x[i], __fmul_rn(xk, A[i*NM+k]));
        }
        for (int k = NM-1; k >= 0; k--) {
            float xk = __fdiv_rn(x[k], A[k*NM+k]);
            x[k] = xk;
            for (int i = 0; i < k; i++) x[i] = __fsub_rn(x[i], __fmul_rn(xk, A[i*NM+k]));
        }
        for (int i = 0; i < NM; i++) Y[i*NM+c] = x[i];
    }
}

// ---------------- 1. per-camera transforms (f32, reference semantics) -------------
__global__ void lss_prep_kernel(const float* __restrict__ l2i,
                                const float* __restrict__ aug,
                                float* __restrict__ mats) {
    int n = threadIdx.x;
    if (n >= BN) return;
    float A[16], IA[16];
    for (int i = 0; i < 16; i++) A[i] = l2i[n*16 + i];
    inv_lu_f32<4>(A, IA);
    float R[9], IR[9];
    for (int i = 0; i < 3; i++)
        for (int j = 0; j < 3; j++) R[i*3+j] = aug[n*16 + i*4 + j];
    inv_lu_f32<3>(R, IR);
    float* o = mats + n*24;
    for (int i = 0; i < 9; i++) o[i] = IR[i];
    o[9]  = aug[n*16 + 3];
    o[10] = aug[n*16 + 7];
    o[11] = aug[n*16 + 11];
    for (int i = 0; i < 3; i++)
        for (int j = 0; j < 3; j++) o[12 + i*3 + j] = IA[i*4 + j];
    o[21] = IA[3]; o[22] = IA[7]; o[23] = IA[11];
}

// ---------------- 2. transpose depthnet weights -> wT[c][96] ----------------
__global__ void lss_wt_kernel(const float* __restrict__ w_dep, float* __restrict__ wT) {
    int idx = blockIdx.x * 256 + threadIdx.x;   // 96*256 = 24576
    int o = idx / CIN, c = idx % CIN;
    wT[c * NOUT + o] = w_dep[idx];
}

// ---------------- 3. geometry: cell per point (f32, np semantics) ----------------
__global__ void lss_geom_kernel(const float* __restrict__ mats,
                                int* __restrict__ cellid,
                                int* __restrict__ counts) {
    int gp = blockIdx.x * 256 + threadIdx.x;    // [0, BN*HW)
    int lane = threadIdx.x & 63;
    int bn = gp / HW, p = gp % HW;
    const float* m = mats + bn * 24;
    int ph = p / WF, pw = p % WF;
    float u = ((float)pw + 0.5f) * 8.0f;
    float v = ((float)ph + 0.5f) * 8.0f;
    float q0 = __fsub_rn(u, m[9]);
    float q1 = __fsub_rn(v, m[10]);
    float q2 = __fsub_rn(1.0f, m[11]);
    float r0 = __fadd_rn(__fadd_rn(__fmul_rn(m[0], q0), __fmul_rn(m[1], q1)), __fmul_rn(m[2], q2));
    float r1 = __fadd_rn(__fadd_rn(__fmul_rn(m[3], q0), __fmul_rn(m[4], q1)), __fmul_rn(m[5], q2));
    float r2 = __fadd_rn(__fadd_rn(__fmul_rn(m[6], q0), __fmul_rn(m[7], q1)), __fmul_rn(m[8], q2));
    int b = bn / NCAM;
    for (int d = 0; d < DBIN; d++) {
        float dv = __fmul_rn((float)d + 0.5f, 2.8125f);
        float p0 = __fmul_rn(r0, dv);
        float p1 = __fmul_rn(r1, dv);
        float p2 = __fmul_rn(r2, dv);
        float px = __fadd_rn(__fadd_rn(__fadd_rn(__fmul_rn(m[12], p0), __fmul_rn(m[13], p1)), __fmul_rn(m[14], p2)), m[21]);
        float py = __fadd_rn(__fadd_rn(__fadd_rn(__fmul_rn(m[15], p0), __fmul_rn(m[16], p1)), __fmul_rn(m[17], p2)), m[22]);
        float pz = __fadd_rn(__fadd_rn(__fadd_rn(__fmul_rn(m[18], p0), __fmul_rn(m[19], p1)), __fmul_rn(m[20], p2)), m[23]);
        float fx = floorf(__fdiv_rn(__fsub_rn(px, -51.2f), 0.8f));
        float fy = floorf(__fdiv_rn(__fsub_rn(py, -51.2f), 0.8f));
        int cell = -1;
        if (fx >= 0.0f && fx < 128.0f && fy >= 0.0f && fy < 128.0f && pz >= -5.0f && pz < 3.0f)
            cell = b * (BEVH * BEVW) + (int)fy * BEVW + (int)fx;
        cellid[(bn * DBIN + d) * HW + p] = cell;
        int cprev = __shfl_up(cell, 1);
        bool leader = (lane == 0) || (cell != cprev);
        unsigned long long L = __ballot(leader);
        unsigned long long above = (lane == 63) ? 0ull : (L >> (lane + 1));
        int runlen = above ? __ffsll(above) : (64 - lane);
        if (leader && cell >= 0) atomicAdd(&counts[cell], runlen);
    }
}

// ---------------- 4. scan counts -> starts, cursors, total (single block) ---------
__global__ void lss_scan_kernel(const int* __restrict__ counts,
                                int* __restrict__ starts,
                                int* __restrict__ cursors) {
    __shared__ int sums[1024];
    int tid = threadIdx.x;
    int base = tid * 32;                 // 32768 / 1024
    int local[32];
    int s = 0;
    #pragma unroll
    for (int i = 0; i < 32; i++) { local[i] = s; s += counts[base + i]; }
    sums[tid] = s;
    __syncthreads();
    for (int off = 1; off < 1024; off <<= 1) {
        int v = 0;
        if (tid >= off) v = sums[tid - off];
        __syncthreads();
        if (tid >= off) sums[tid] += v;
        __syncthreads();
    }
    int offset = (tid > 0) ? sums[tid - 1] : 0;
    #pragma unroll
    for (int i = 0; i < 32; i++) {
        int st = offset + local[i];
        starts[base + i]  = st;
        cursors[base + i] = st;
    }
    if (tid == 1023) starts[NUMC] = sums[1023];   // total valid
}

// ---------------- 5. fill CSR (run-aggregated atomics, fused index) ---------------
__global__ void lss_fill_kernel(const int* __restrict__ cellid,
                                int* __restrict__ cursors,
                                int* __restrict__ plist,
                                int* __restrict__ pcell) {
    int i = blockIdx.x * 256 + threadIdx.x;    // NPTS = 2112*256
    int lane = threadIdx.x & 63;
    int c = cellid[i];
    int bn  = i / (DBIN * HW);
    int rem = i % (DBIN * HW);
    int d   = rem / HW;
    int p   = rem % HW;
    int pf  = ((bn * HW + p) << 4) | d;
    int cprev = __shfl_up(c, 1);
    bool leader = (lane == 0) || (c != cprev);
    unsigned long long L = __ballot(leader);
    unsigned long long above = (lane == 63) ? 0ull : (L >> (lane + 1));
    int runlen = above ? __ffsll(above) : (64 - lane);
    unsigned long long below = L & (~0ull >> (63 - lane));
    int lead = 63 - __clzll(below);
    int rank = lane - lead;
    int bse = 0;
    if (leader && c >= 0) bse = atomicAdd(&cursors[c], runlen);
    bse = __shfl(bse, lead);
    if (c >= 0) {
        plist[bse + rank] = pf;
        pcell[bse + rank] = c;
    }
}

// ---------------- 6. depthnet GEMM + softmax, ILP-deep streaming ------------------
// block: 256 thr = 4 waves; wave w -> o-group [24w, 24w+24); all waves share the
// block's 128 pixels (lane -> 2 consecutive px, one float2 load per c).
// K=256 chunked x16: 16 independent global loads in flight, then 16x48 FMAs.
// No LDS, no barriers. Sequential c order (same FP order as r3/r4 kernel).
__global__ __launch_bounds__(256) void lss_gemm_kernel(const float* __restrict__ x,
                                                       const float* __restrict__ wT,
                                                       const float* __restrict__ b_dep,
                                                       float* __restrict__ yT) {
    int lane = threadIdx.x & 63;
    int wv   = threadIdx.x >> 6;
    int ob   = wv * 24;
    int px0  = blockIdx.x * 128 + lane * 2;   // 264 blocks; HW=22*128 -> bn uniform
    int bn = px0 / HW, p = px0 % HW;
    const float* xp = x + (size_t)bn * CIN * HW + p;
    float acc[24][2];
    #pragma unroll
    for (int o = 0; o < 24; o++) { acc[o][0] = 0.f; acc[o][1] = 0.f; }

    for (int cc = 0; cc < CIN; cc += 16) {
        float2 xb[16];
        #pragma unroll
        for (int u = 0; u < 16; u++)
            xb[u] = *(const float2*)(xp + (size_t)(cc + u) * HW);
        #pragma unroll
        for (int u = 0; u < 16; u++) {
            const float* wc = wT + (cc + u) * NOUT + ob;   // uniform -> s_load
            #pragma unroll
            for (int o = 0; o < 24; o++) {
                acc[o][0] = fmaf(wc[o], xb[u].x, acc[o][0]);
                acc[o][1] = fmaf(wc[o], xb[u].y, acc[o][1]);
            }
        }
    }
    #pragma unroll
    for (int o = 0; o < 24; o++) {
        float bi = b_dep[ob + o];
        acc[o][0] += bi;
        acc[o][1] += bi;
    }
    if (wv == 0) {
        #pragma unroll
        for (int j = 0; j < 2; j++) {
            float* yp = yT + (size_t)(px0 + j) * NOUT;
            float m = acc[0][j];
            #pragma unroll
            for (int o = 1; o < 16; o++) m = fmaxf(m, acc[o][j]);
            float e[16], s = 0.f;
            #pragma unroll
            for (int o = 0; o < 16; o++) { e[o] = expf(acc[o][j] - m); s += e[o]; }
            float inv = 1.f / s;
            #pragma unroll
            for (int o = 0; o < 16; o++) yp[o] = e[o] * inv;
            #pragma unroll
            for (int o = 16; o < 24; o++) yp[o] = acc[o][j];
        }
    } else {
        #pragma unroll
        for (int j = 0; j < 2; j++) {
            float* yp = yT + (size_t)(px0 + j) * NOUT + ob;
            #pragma unroll
            for (int o = 0; o < 24; o++) yp[o] = acc[o][j];
        }
    }
}

// ---------------- 7. chunked segmented gather -> bevHWC (atomic flush) ------------
__global__ __launch_bounds__(256) void lss_gather_kernel(const float* __restrict__ yT,
                                                         const int* __restrict__ plist,
                                                         const int* __restrict__ pcell,
                                                         const int* __restrict__ nvptr,
                                                         float* __restrict__ bevHWC) {
    int wv   = threadIdx.x >> 6;
    int lane = threadIdx.x & 63;
    int pos0 = (blockIdx.x * 4 + wv) * 64;
    int nv = *nvptr;
    if (pos0 >= nv) return;
    int n = min(64, nv - pos0);
    const int* pl = plist + pos0;
    const int* pc = pcell + pos0;
    float a0 = 0.f, a1 = 0.f;
    int cur = pc[0];
    for (int j = 0; j < n; j++) {
        int c = pc[j];                     // wave-uniform
        if (c != cur) {
            atomicAdd(&bevHWC[(size_t)cur * COUT + lane], a0);
            if (lane < 16) atomicAdd(&bevHWC[(size_t)cur * COUT + 64 + lane], a1);
            a0 = a1 = 0.f;
            cur = c;
        }
        int pf = pl[j];
        const float* yp = yT + (size_t)(pf >> 4) * NOUT;
        float dep = yp[pf & 15];
        a0 = fmaf(dep, yp[16 + lane], a0);
        if (lane < 16) a1 = fmaf(dep, yp[80 + lane], a1);
    }
    atomicAdd(&bevHWC[(size_t)cur * COUT + lane], a0);
    if (lane < 16) atomicAdd(&bevHWC[(size_t)cur * COUT + 64 + lane], a1);
}

// ---------------- 8. transpose HWC->CHW + normalize by count ----------------------
__global__ __launch_bounds__(256) void lss_tr_kernel(const float* __restrict__ bevHWC,
                                                     const int* __restrict__ counts,
                                                     float* __restrict__ bevCHW) {
    __shared__ float t[COUT][65];
    __shared__ float ic[64];
    int tid = threadIdx.x;
    int cellbase = blockIdx.x * 64;
    if (tid < 64) {
        int cnt = counts[cellbase + tid];
        ic[tid] = 1.f / fmaxf((float)cnt, 1.f);
    }
    const float* src = bevHWC + (size_t)cellbase * COUT;
    #pragma unroll
    for (int k = 0; k < 20; k++) {
        int idx = tid + k * 256;           // 5120 = 20*256
        int yx = idx / COUT, ch = idx % COUT;
        t[ch][yx] = src[idx];
    }
    __syncthreads();
    int b  = cellbase >> 14;
    int yx0 = cellbase & 16383;
    #pragma unroll
    for (int k = 0; k < 20; k++) {
        int idx = tid + k * 256;
        int ch = idx / 64, yxl = idx % 64;
        bevCHW[((size_t)(b * COUT + ch)) * (BEVH * BEVW) + yx0 + yxl] = t[ch][yxl] * ic[yxl];
    }
}

// ---------------- 9. 3x3 SAME conv — barrier-free register-window streaming -------
__global__ __launch_bounds__(256) void lss_conv_kernel(const float* __restrict__ bev,
                                                       const float* __restrict__ w,
                                                       const float* __restrict__ bias,
                                                       float* __restrict__ out) {
    int bx = blockIdx.x;               // 0..63 = b*32 + ytile
    int og = blockIdx.y * 8;           // 10 groups
    int b  = bx >> 5;
    int y0 = (bx & 31) * 4;
    int x  = threadIdx.x & 127;
    int rg = threadIdx.x >> 7;         // 0 or 1
    int yb = y0 + rg * 2;              // first out row of this thread

    int offs[4][3];
    float msk[4][3];
    #pragma unroll
    for (int r = 0; r < 4; r++) {
        int yy = yb + r - 1;
        float ym = (yy >= 0 && yy < 128) ? 1.f : 0.f;
        int yc = min(max(yy, 0), 127);
        #pragma unroll
        for (int c = 0; c < 3; c++) {
            int xx = x + c - 1;
            float xm = (xx >= 0 && xx < 128) ? 1.f : 0.f;
            int xc = min(max(xx, 0), 127);
            offs[r][c] = yc * BEVW + xc;
            msk[r][c]  = ym * xm;
        }
    }

    float acc[8][2];
    #pragma unroll
    for (int o = 0; o < 8; o++) { acc[o][0] = 0.f; acc[o][1] = 0.f; }

    const float* pb = bev + (size_t)b * COUT * (BEVH * BEVW);
    for (int ci = 0; ci < COUT; ci++) {
        const float* pc = pb + (size_t)ci * (BEVH * BEVW);
        float win[4][3];
        #pragma unroll
        for (int r = 0; r < 4; r++)
            #pragma unroll
            for (int c = 0; c < 3; c++)
                win[r][c] = pc[offs[r][c]] * msk[r][c];
        #pragma unroll
        for (int o = 0; o < 8; o++) {
            const float* wp = w + ((size_t)(og + o) * COUT + ci) * 9;   // uniform -> s_load
            #pragma unroll
            for (int j = 0; j < 2; j++) {
                float a = acc[o][j];
                a = fmaf(wp[0], win[j][0],     a);
                a = fmaf(wp[1], win[j][1],     a);
                a = fmaf(wp[2], win[j][2],     a);
                a = fmaf(wp[3], win[j + 1][0], a);
                a = fmaf(wp[4], win[j + 1][1], a);
                a = fmaf(wp[5], win[j + 1][2], a);
                a = fmaf(wp[6], win[j + 2][0], a);
                a = fmaf(wp[7], win[j + 2][1], a);
                a = fmaf(wp[8], win[j + 2][2], a);
                acc[o][j] = a;
            }
        }
    }
    #pragma unroll
    for (int o = 0; o < 8; o++) {
        float bi = bias[og + o];
        #pragma unroll
        for (int j = 0; j < 2; j++)
            out[((size_t)(b * COUT + og + o) * BEVH + (yb + j)) * BEVW + x] = acc[o][j] + bi;
    }
}

// ---------------- launch ----------------
extern "C" void kernel_launch(void* const* d_in, const int* in_sizes, int n_in,
                              void* d_out, int out_size, void* d_ws, size_t ws_size,
                              hipStream_t stream) {
    (void)in_sizes; (void)n_in; (void)out_size; (void)ws_size;
    const float* x     = (const float*)d_in[0];
    const float* l2i   = (const float*)d_in[1];
    const float* aug   = (const float*)d_in[2];
    const float* w_dep = (const float*)d_in[3];
    const float* b_dep = (const float*)d_in[4];
    const float* w_ref = (const float*)d_in[5];
    const float* b_ref = (const float*)d_in[6];
    float* out = (float*)d_out;

    char* ws = (char*)d_ws;
    float* mats    = (float*)(ws + MATS_OFF);
    float* wT      = (float*)(ws + WT_OFF);
    float* yT      = (float*)(ws + YT_OFF);     // reused as bevCHW after gather
    float* bevCHW  = (float*)(ws + YT_OFF);
    int*   cellid  = (int*)(ws + CELL_OFF);
    int*   counts  = (int*)(ws + COUNTS_OFF);
    int*   starts  = (int*)(ws + STARTS_OFF);
    int*   cursors = (int*)(ws + CURS_OFF);
    int*   plist   = (int*)(ws + PLIST_OFF);
    int*   pcell   = (int*)(ws + PCELL_OFF);
    float* bevHWC  = (float*)(ws + BEVHWC_OFF);

    hipMemsetAsync(counts, 0, NUMC * sizeof(int), stream);
    hipMemsetAsync(bevHWC, 0, (size_t)NUMC * COUT * sizeof(float), stream);
    lss_prep_kernel<<<1, 64, 0, stream>>>(l2i, aug, mats);
    lss_wt_kernel<<<96, 256, 0, stream>>>(w_dep, wT);
    lss_geom_kernel<<<BN * HW / 256, 256, 0, stream>>>(mats, cellid, counts);
    lss_scan_kernel<<<1, 1024, 0, stream>>>(counts, starts, cursors);
    lss_fill_kernel<<<NPTS / 256, 256, 0, stream>>>(cellid, cursors, plist, pcell);
    lss_gemm_kernel<<<264, 256, 0, stream>>>(x, wT, b_dep, yT);
    lss_gather_kernel<<<NPTS / 256, 256, 0, stream>>>(yT, plist, pcell, starts + NUMC, bevHWC);
    lss_tr_kernel<<<NUMC / 64, 256, 0, stream>>>(bevHWC, counts, bevCHW);
    lss_conv_kernel<<<dim3(64, 10), 256, 0, stream>>>(bevCHW, w_ref, b_ref, out);
}